// Round 7
// baseline (58.449 us; speedup 1.0000x reference)
//
#include <hip/hip_runtime.h>
#include <stdint.h>

#define BLOCK  256
#define NW     4                 // waves per block
#define CHPG   8                 // channels per group (2 per wave)
#define NG     8                 // groups per block -> 64 channels/block
#define SB_CH  1024              // floats per channel of search
#define SBUF_G (CHPG * SB_CH)    // 8192 floats per search buffer
#define KBUF_G (CHPG * 64)       // 512 floats per kernel buffer

// async global->LDS, 16B per lane; LDS dest wave-uniform, writes base+lane*16
__device__ __forceinline__ void gl_lds16(const float* g, float* l) {
    __builtin_amdgcn_global_load_lds(
        (__attribute__((address_space(1))) void*)(uintptr_t)g,
        (__attribute__((address_space(3))) void*)l, 16, 0, 0);
}
// 4B per lane variant
__device__ __forceinline__ void gl_lds4(const float* g, float* l) {
    __builtin_amdgcn_global_load_lds(
        (__attribute__((address_space(1))) void*)(uintptr_t)g,
        (__attribute__((address_space(3))) void*)l, 4, 0, 0);
}

// Per-wave staging of its OWN 2 channels: exactly 10 vmem-lds ops/wave.
__device__ __forceinline__ void stage_group(
    const float* __restrict__ srch, const float* __restrict__ kern,
    float* s_s, float* s_k, int cg, int w, int lane, int p)
{
    const int cA = cg + 2 * w;
    const float* gs = srch + (size_t)cA * SB_CH;
    float* ls = s_s + p * SBUF_G + w * 2048;
    #pragma unroll
    for (int t = 0; t < 8; ++t)
        gl_lds16(gs + t * 256 + lane * 4, ls + t * 256);   // 8 x 1024B
    const float* gk = kern + (size_t)cA * 64;
    float* lk = s_k + p * KBUF_G + w * 128;
    #pragma unroll
    for (int t = 0; t < 2; ++t)
        gl_lds4(gk + t * 64 + lane, lk + t * 64);          // 2 x 256B
}

// Compute one group's 2 channels for this wave. Exactly 25 store instrs/wave.
__device__ __forceinline__ void compute_group(
    const float* s_s, const float* s_k, float* __restrict__ out,
    int cg, int w, int lane, int p, bool act)
{
    const int h  = lane >> 5;
    const int j  = lane & 31;
    const int ch = cg + 2 * w + h;
    const float* sb = s_s + p * SBUF_G + w * 2048 + h * SB_CH + j;
    const float* kb = s_k + p * KBUF_G + w * 128 + h * 64;

    if (act) {  // j < 25
        float kk[64];
        #pragma unroll
        for (int t = 0; t < 16; ++t) {     // broadcast b128 reads (uniform per half)
            float4 kv = ((const float4*)kb)[t];
            kk[4*t+0] = kv.x; kk[4*t+1] = kv.y; kk[4*t+2] = kv.z; kk[4*t+3] = kv.w;
        }
        float acc[25];
        #pragma unroll
        for (int i = 0; i < 25; ++i) acc[i] = 0.0f;

        #pragma unroll
        for (int r = 0; r < 32; ++r) {
            float sv[8];
            #pragma unroll
            for (int v = 0; v < 8; ++v) sv[v] = sb[r * 32 + v];  // bank=(j+v)%32: conflict-free
            const int lo = (r > 24) ? (r - 24) : 0;
            const int hi = (r < 7) ? r : 7;
            #pragma unroll
            for (int u = 0; u < 8; ++u) {
                if (u >= lo && u <= hi) {
                    #pragma unroll
                    for (int v = 0; v < 8; ++v)
                        acc[r - u] = fmaf(kk[u * 8 + v], sv[v], acc[r - u]);
                }
            }
        }
        float* op = out + (size_t)ch * 625 + j;
        #pragma unroll
        for (int i = 0; i < 25; ++i) op[i * 25] = acc[i];
    }
}

#define WAITV(N) do { \
    asm volatile("s_waitcnt vmcnt(" #N ")" ::: "memory"); \
    __builtin_amdgcn_sched_barrier(0); \
} while (0)

__global__ __launch_bounds__(BLOCK, 2) void dwxcorr_kernel(
    const float* __restrict__ kern,
    const float* __restrict__ srch,
    float* __restrict__ out)
{
    __shared__ float s_s[2 * SBUF_G];   // 65536 B
    __shared__ float s_k[2 * KBUF_G];   //  4096 B  -> 2 blocks/CU

    const int tid  = threadIdx.x;
    const int w    = tid >> 6;
    const int lane = tid & 63;
    const bool act = ((lane & 31) < 25);
    const int c0   = blockIdx.x * (CHPG * NG);

    // prologue: prefetch group 0
    stage_group(srch, kern, s_s, s_k, c0, w, lane, 0);

    // g = 0: prefetch g1; ops newer than stage(0) = 10 -> vmcnt(10)
    stage_group(srch, kern, s_s, s_k, c0 + CHPG, w, lane, 1);
    WAITV(10);
    compute_group(s_s, s_k, out, c0, w, lane, 0, act);

    // middle g = 1 .. NG-2: newer-than-stage(g) = 25 stores(g-1) + 10 loads(g+1)
    #pragma unroll 1
    for (int g = 1; g <= NG - 2; ++g) {
        stage_group(srch, kern, s_s, s_k, c0 + (g + 1) * CHPG, w, lane, (g + 1) & 1);
        WAITV(35);
        compute_group(s_s, s_k, out, c0 + g * CHPG, w, lane, g & 1, act);
    }

    // tail g = NG-1: newer-than-stage(NG-1) = 25 stores(NG-2)
    WAITV(25);
    compute_group(s_s, s_k, out, c0 + (NG - 1) * CHPG, w, lane, (NG - 1) & 1, act);
}

extern "C" void kernel_launch(void* const* d_in, const int* in_sizes, int n_in,
                              void* d_out, int out_size, void* d_ws, size_t ws_size,
                              hipStream_t stream) {
    const float* kern = (const float*)d_in[0];   // (128,256,8,8)
    const float* srch = (const float*)d_in[1];   // (128,256,32,32)
    float* out = (float*)d_out;                  // (128,256,25,25)

    const int nch  = in_sizes[0] / 64;           // 32768
    const int grid = nch / (CHPG * NG);          // 512 (exact)
    dwxcorr_kernel<<<grid, BLOCK, 0, stream>>>(kern, srch, out);
}